// Round 6
// baseline (314.389 us; speedup 1.0000x reference)
//
#include <hip/hip_runtime.h>
#include <math.h>

#define N_NODES 100000
#define N_EDGES 1600000
#define F_IN 256
#define HIDDEN 64
#define NEG_SLOPE 0.2f

#define BSHIFT 7               // bucket = dst>>7 (128 nodes/bucket)
#define BMASK 127
#define W_BUCKETS 782          // ceil(100000/128)
#define B_SC 512               // hist/scatter blocks
#define CHUNK 3125             // 512*3125 = 1600000 exactly
#define M_OFF (W_BUCKETS * B_SC)  // 400384
#define NB1 1564               // ceil(M_OFF/256)
#define CAP 2560               // LDS edge capacity per bucket

// ---- K0: fold att_src/att_dst/fc_w through lin_w ----
__global__ __launch_bounds__(256) void prep_kernel(
        const float* __restrict__ lin_w, const float* __restrict__ att_src,
        const float* __restrict__ att_dst, const float* __restrict__ fc_w,
        const float* __restrict__ bias, const float* __restrict__ fc_b,
        float* __restrict__ w_all, float* __restrict__ c0) {
    __shared__ float red[256];
    int h = blockIdx.x;   // 0..3
    int f = threadIdx.x;  // 0..255
    float a0 = 0.f, a1 = 0.f, a2 = 0.f;
    for (int c = 0; c < HIDDEN; ++c) {
        float lw = lin_w[(size_t)(h * HIDDEN + c) * F_IN + f];
        a0 += att_src[h * HIDDEN + c] * lw;
        a1 += att_dst[h * HIDDEN + c] * lw;
        a2 += fc_w[h * HIDDEN + c] * lw;
    }
    w_all[(0 + h) * F_IN + f] = a0;
    w_all[(4 + h) * F_IN + f] = a1;
    w_all[(8 + h) * F_IN + f] = a2;
    if (h == 0) {
        red[f] = bias[f] * fc_w[f];
        __syncthreads();
        for (int s = 128; s; s >>= 1) {
            if (f < s) red[f] += red[f + s];
            __syncthreads();
        }
        if (f == 0) c0[0] = red[0] + fc_b[0];
    }
}

// ---- K1: per-node 256x12 matvec, 16 nodes/wave, w cached in registers ----
// 16-lane group handles 4 nodes; per k-step the 12 w float4s are loaded once
// and reused across the 4 x rows (cuts L1 traffic ~3.3x vs 1 node/group).
__global__ __launch_bounds__(256) void node_kernel(
        const float* __restrict__ x, const float* __restrict__ w_all,
        float* __restrict__ srcfeat, float* __restrict__ dstfeat) {
    int tid  = blockIdx.x * 256 + threadIdx.x;
    int wave = tid >> 6;
    int lane = threadIdx.x & 63;
    int sub  = lane >> 4;
    int l16  = lane & 15;
    int nbase = wave * 16 + sub * 4;   // 4 nodes per 16-lane group
    const float4* xr = (const float4*)x;
    const float4* wr = (const float4*)w_all;
    float p[4][12];
#pragma unroll
    for (int j = 0; j < 4; ++j)
#pragma unroll
        for (int r = 0; r < 12; ++r) p[j][r] = 0.f;

#pragma unroll
    for (int k = 0; k < 4; ++k) {
        float4 wv[12];
#pragma unroll
        for (int r = 0; r < 12; ++r) wv[r] = wr[r * 64 + l16 + 16 * k];
#pragma unroll
        for (int j = 0; j < 4; ++j) {
            int n = nbase + j;
            float4 xv = make_float4(0.f, 0.f, 0.f, 0.f);
            if (n < N_NODES) xv = xr[(size_t)n * 64 + l16 + 16 * k];
#pragma unroll
            for (int r = 0; r < 12; ++r) {
                p[j][r] += xv.x * wv[r].x + xv.y * wv[r].y
                         + xv.z * wv[r].z + xv.w * wv[r].w;
            }
        }
    }
#pragma unroll
    for (int j = 0; j < 4; ++j) {
#pragma unroll
        for (int r = 0; r < 12; ++r) {
            float v = p[j][r];
            v += __shfl_xor(v, 1);
            v += __shfl_xor(v, 2);
            v += __shfl_xor(v, 4);
            v += __shfl_xor(v, 8);
            p[j][r] = v;
        }
    }
    if (l16 == 0) {
#pragma unroll
        for (int j = 0; j < 4; ++j) {
            int n = nbase + j;
            if (n < N_NODES) {
                float4* sf = (float4*)(srcfeat + (size_t)n * 8);
                sf[0] = make_float4(p[j][0], p[j][1], p[j][2], p[j][3]);
                sf[1] = make_float4(p[j][8], p[j][9], p[j][10], p[j][11]);
                *(float4*)(dstfeat + (size_t)n * 4) =
                    make_float4(p[j][4], p[j][5], p[j][6], p[j][7]);
            }
        }
    }
}

// =================== LDS-privatized counting sort (bucket = 128 nodes) ===================

__global__ __launch_bounds__(256) void hist2_kernel(
        const int* __restrict__ ei, int* __restrict__ hist) {
    __shared__ int lcnt[W_BUCKETS];
    int t = threadIdx.x, b = blockIdx.x;
    for (int i = t; i < W_BUCKETS; i += 256) lcnt[i] = 0;
    __syncthreads();
    int base = b * CHUNK;
    int end = base + CHUNK; if (end > N_EDGES) end = N_EDGES;
    for (int e = base + t; e < end; e += 256)
        atomicAdd(&lcnt[ei[N_EDGES + e] >> BSHIFT], 1);
    __syncthreads();
    for (int i = t; i < W_BUCKETS; i += 256) hist[i * B_SC + b] = lcnt[i];
}

__global__ __launch_bounds__(256) void scan1_kernel(
        const int* __restrict__ hist, int* __restrict__ bsum) {
    __shared__ int red[256];
    int t = threadIdx.x, b = blockIdx.x;
    int i = b * 256 + t;
    red[t] = (i < M_OFF) ? hist[i] : 0;
    __syncthreads();
    for (int s = 128; s; s >>= 1) {
        if (t < s) red[t] += red[t + s];
        __syncthreads();
    }
    if (t == 0) bsum[b] = red[0];
}

// exclusive scan of NB1 block sums; 1024 threads x 2 serial
__global__ __launch_bounds__(1024) void scan2_kernel(int* __restrict__ bsum) {
    __shared__ int sc[1024];
    int t = threadIdx.x;
    int i0 = t * 2, i1 = t * 2 + 1;
    int v0 = (i0 < NB1) ? bsum[i0] : 0;
    int v1 = (i1 < NB1) ? bsum[i1] : 0;
    int s = v0 + v1;
    sc[t] = s;
    __syncthreads();
    for (int off = 1; off < 1024; off <<= 1) {
        int tmp = (t >= off) ? sc[t - off] : 0;
        __syncthreads();
        sc[t] += tmp;
        __syncthreads();
    }
    int base = sc[t] - s;  // exclusive
    if (i0 < NB1) bsum[i0] = base;
    if (i1 < NB1) bsum[i1] = base + v0;
}

__global__ __launch_bounds__(256) void scan3_kernel(
        int* __restrict__ hist, const int* __restrict__ bsum) {
    __shared__ int sc[256];
    int t = threadIdx.x, b = blockIdx.x;
    int i = b * 256 + t;
    int v = (i < M_OFF) ? hist[i] : 0;
    sc[t] = v;
    __syncthreads();
    for (int off = 1; off < 256; off <<= 1) {
        int tmp = (t >= off) ? sc[t - off] : 0;
        __syncthreads();
        sc[t] += tmp;
        __syncthreads();
    }
    if (i < M_OFF) hist[i] = bsum[b] + sc[t] - v;
}

// place edges: sorted[pos] = src | (dst&127)<<17
__global__ __launch_bounds__(256) void scatter2_kernel(
        const int* __restrict__ ei, const int* __restrict__ goff,
        int* __restrict__ sorted) {
    __shared__ int lbase[W_BUCKETS];
    int t = threadIdx.x, b = blockIdx.x;
    for (int i = t; i < W_BUCKETS; i += 256) lbase[i] = goff[i * B_SC + b];
    __syncthreads();
    int base = b * CHUNK;
    int end = base + CHUNK; if (end > N_EDGES) end = N_EDGES;
    for (int e = base + t; e < end; e += 256) {
        int s = ei[e];
        int d = ei[N_EDGES + e];
        int pos = atomicAdd(&lbase[d >> BSHIFT], 1);
        sorted[pos] = s | ((d & BMASK) << 17);
    }
}

// ---- agg4: per-bucket in-LDS fine sort + atomic-free per-node aggregation ----
__global__ __launch_bounds__(256) void agg4_kernel(
        const int* __restrict__ sorted, const int* __restrict__ goff,
        const float* __restrict__ srcfeat, const float* __restrict__ dstfeat,
        const float* __restrict__ c0, float* __restrict__ out) {
    __shared__ int eds[CAP];
    __shared__ int srt[CAP];
    __shared__ int cnt[128];   // hist, then cursor
    __shared__ int bnd[129];   // exclusive bounds
    int t = threadIdx.x, k = blockIdx.x;
    int begin = goff[k * B_SC];
    int end = (k == W_BUCKETS - 1) ? N_EDGES : goff[(k + 1) * B_SC];
    int len = end - begin;
    int lcap = len < CAP ? len : CAP;
    if (t < 128) cnt[t] = 0;
    __syncthreads();
    for (int i = t; i < lcap; i += 256) {
        int p = sorted[begin + i];
        eds[i] = p;
        atomicAdd(&cnt[p >> 17], 1);
    }
    __syncthreads();
    if (t < 128) bnd[t + 1] = cnt[t];
    __syncthreads();
    for (int off = 1; off < 128; off <<= 1) {
        int v = 0;
        if (t < 128 && t >= off) v = bnd[t + 1 - off];
        __syncthreads();
        if (t < 128) bnd[t + 1] += v;
        __syncthreads();
    }
    if (t == 0) bnd[0] = 0;
    if (t < 128) cnt[t] = (t == 0) ? 0 : bnd[t];
    __syncthreads();
    for (int i = t; i < lcap; i += 256) {
        int p = eds[i];
        int pos = atomicAdd(&cnt[p >> 17], 1);
        srt[pos] = p & 0x1FFFF;
    }
    __syncthreads();
    if (t < 128) {
        int n0 = k * 128 + t;
        if (n0 < N_NODES) {
            float4 ad = *(const float4*)(dstfeat + (size_t)n0 * 4);
            float de0 = 0.f, de1 = 0.f, de2 = 0.f, de3 = 0.f;
            float nu0 = 0.f, nu1 = 0.f, nu2 = 0.f, nu3 = 0.f;
            int b0 = bnd[t], e0 = bnd[t + 1];
            for (int i = b0; i < e0; ++i) {
                int s = srt[i];
                const float4* sp = (const float4*)(srcfeat + (size_t)s * 8);
                float4 as = sp[0];
                float4 g  = sp[1];
                float s0 = as.x + ad.x, s1 = as.y + ad.y;
                float s2 = as.z + ad.z, s3 = as.w + ad.w;
                float x0 = __expf(s0 > 0.f ? s0 : NEG_SLOPE * s0);
                float x1 = __expf(s1 > 0.f ? s1 : NEG_SLOPE * s1);
                float x2 = __expf(s2 > 0.f ? s2 : NEG_SLOPE * s2);
                float x3 = __expf(s3 > 0.f ? s3 : NEG_SLOPE * s3);
                de0 += x0; de1 += x1; de2 += x2; de3 += x3;
                nu0 += x0 * g.x; nu1 += x1 * g.y; nu2 += x2 * g.z; nu3 += x3 * g.w;
            }
            for (int i = CAP; i < len; ++i) {
                int p = sorted[begin + i];
                if ((p >> 17) == t) {
                    int s = p & 0x1FFFF;
                    const float4* sp = (const float4*)(srcfeat + (size_t)s * 8);
                    float4 as = sp[0];
                    float4 g  = sp[1];
                    float s0 = as.x + ad.x, s1 = as.y + ad.y;
                    float s2 = as.z + ad.z, s3 = as.w + ad.w;
                    float x0 = __expf(s0 > 0.f ? s0 : NEG_SLOPE * s0);
                    float x1 = __expf(s1 > 0.f ? s1 : NEG_SLOPE * s1);
                    float x2 = __expf(s2 > 0.f ? s2 : NEG_SLOPE * s2);
                    float x3 = __expf(s3 > 0.f ? s3 : NEG_SLOPE * s3);
                    de0 += x0; de1 += x1; de2 += x2; de3 += x3;
                    nu0 += x0 * g.x; nu1 += x1 * g.y; nu2 += x2 * g.z; nu3 += x3 * g.w;
                }
            }
            float y = c0[0]
                    + nu0 / (de0 + 1e-16f)
                    + nu1 / (de1 + 1e-16f)
                    + nu2 / (de2 + 1e-16f)
                    + nu3 / (de3 + 1e-16f);
            out[n0] = y;
        }
    }
}

// =================== fallback atomic path (tiny ws) ===================

__global__ __launch_bounds__(256) void init_nd_kernel(
        float* __restrict__ num, float* __restrict__ den) {
    int i = blockIdx.x * 256 + threadIdx.x;
    if (i < N_NODES * 4) { num[i] = 0.f; den[i] = 0.f; }
}

__global__ __launch_bounds__(256) void edge_acc2_kernel(
        const int* __restrict__ ei, const float* __restrict__ srcfeat,
        const float* __restrict__ dstfeat, float* __restrict__ num,
        float* __restrict__ den) {
    int e = blockIdx.x * 256 + threadIdx.x;
    if (e >= N_EDGES) return;
    int s = ei[e];
    int d = ei[N_EDGES + e];
    const float4* sp = (const float4*)(srcfeat + (size_t)s * 8);
    float4 as = sp[0];
    float4 g  = sp[1];
    float4 ad = *(const float4*)(dstfeat + (size_t)d * 4);
    float sc[4] = {as.x + ad.x, as.y + ad.y, as.z + ad.z, as.w + ad.w};
    float gg[4] = {g.x, g.y, g.z, g.w};
    float* np = num + (size_t)d * 4;
    float* dp = den + (size_t)d * 4;
#pragma unroll
    for (int h = 0; h < 4; ++h) {
        float v = sc[h] > 0.f ? sc[h] : NEG_SLOPE * sc[h];
        float ex = __expf(v);
        atomicAdd(dp + h, ex);
        atomicAdd(np + h, ex * gg[h]);
    }
}

__global__ __launch_bounds__(256) void finalize_kernel(
        const float* __restrict__ num, const float* __restrict__ den,
        const float* __restrict__ c0, float* __restrict__ out) {
    int n = blockIdx.x * 256 + threadIdx.x;
    if (n >= N_NODES) return;
    float4 nu = *(const float4*)(num + (size_t)n * 4);
    float4 de = *(const float4*)(den + (size_t)n * 4);
    out[n] = c0[0]
           + nu.x / (de.x + 1e-16f)
           + nu.y / (de.y + 1e-16f)
           + nu.z / (de.z + 1e-16f)
           + nu.w / (de.w + 1e-16f);
}

extern "C" void kernel_launch(void* const* d_in, const int* in_sizes, int n_in,
                              void* d_out, int out_size, void* d_ws, size_t ws_size,
                              hipStream_t stream) {
    const float* x       = (const float*)d_in[0];
    const int*   ei      = (const int*)d_in[1];
    const float* lin_w   = (const float*)d_in[2];
    const float* att_src = (const float*)d_in[3];
    const float* att_dst = (const float*)d_in[4];
    const float* bias    = (const float*)d_in[5];
    const float* fc_w    = (const float*)d_in[6];
    const float* fc_b    = (const float*)d_in[7];
    float* out = (float*)d_out;

    float* ws = (float*)d_ws;
    float* w_all   = ws;            // 3072 (+pad to 4096)
    float* c0      = ws + 3072;
    float* srcfeat = ws + 4096;     // 800000
    float* dstfeat = ws + 804096;   // 400000

    prep_kernel<<<4, 256, 0, stream>>>(lin_w, att_src, att_dst, fc_w, bias, fc_b, w_all, c0);
    // 16 nodes per wave, 64 nodes per block
    node_kernel<<<(N_NODES + 63) / 64, 256, 0, stream>>>(x, w_all, srcfeat, dstfeat);

    // layout: hist @1204096 (400384) | bsum @1604480 (1564, pad) | sorted @1606144 (1600000)
    const size_t need_words = 3206144;
    if (ws_size >= need_words * 4) {
        int* hist   = (int*)(ws + 1204096);
        int* bsum   = (int*)(ws + 1604480);
        int* sorted = (int*)(ws + 1606144);

        hist2_kernel<<<B_SC, 256, 0, stream>>>(ei, hist);
        scan1_kernel<<<NB1, 256, 0, stream>>>(hist, bsum);
        scan2_kernel<<<1, 1024, 0, stream>>>(bsum);
        scan3_kernel<<<NB1, 256, 0, stream>>>(hist, bsum);
        scatter2_kernel<<<B_SC, 256, 0, stream>>>(ei, hist, sorted);
        agg4_kernel<<<W_BUCKETS, 256, 0, stream>>>(sorted, hist, srcfeat, dstfeat, c0, out);
    } else {
        float* num = ws + 1204096;
        float* den = ws + 1604096;
        init_nd_kernel<<<(N_NODES * 4 + 255) / 256, 256, 0, stream>>>(num, den);
        edge_acc2_kernel<<<N_EDGES / 256, 256, 0, stream>>>(ei, srcfeat, dstfeat, num, den);
        finalize_kernel<<<(N_NODES + 255) / 256, 256, 0, stream>>>(num, den, c0, out);
    }
}

// Round 7
// 243.492 us; speedup vs baseline: 1.2912x; 1.2912x over previous
//
#include <hip/hip_runtime.h>
#include <math.h>

#define N_NODES 100000
#define N_EDGES 1600000
#define F_IN 256
#define HIDDEN 64
#define NEG_SLOPE 0.2f

#define BSHIFT 7               // bucket = dst>>7 (128 nodes/bucket)
#define BMASK 127
#define W_BUCKETS 782          // ceil(100000/128)
#define B_SC 512               // hist/scatter blocks
#define CHUNK 3125             // 512*3125 = 1600000 exactly
#define M_OFF (W_BUCKETS * B_SC)  // 400384
#define NB1 1564               // ceil(M_OFF/256)
#define CAP 2560               // LDS edge capacity per bucket

// ---- K0: fold att_src/att_dst/fc_w through lin_w ----
__global__ __launch_bounds__(256) void prep_kernel(
        const float* __restrict__ lin_w, const float* __restrict__ att_src,
        const float* __restrict__ att_dst, const float* __restrict__ fc_w,
        const float* __restrict__ bias, const float* __restrict__ fc_b,
        float* __restrict__ w_all, float* __restrict__ c0) {
    __shared__ float red[256];
    int h = blockIdx.x;   // 0..3
    int f = threadIdx.x;  // 0..255
    float a0 = 0.f, a1 = 0.f, a2 = 0.f;
    for (int c = 0; c < HIDDEN; ++c) {
        float lw = lin_w[(size_t)(h * HIDDEN + c) * F_IN + f];
        a0 += att_src[h * HIDDEN + c] * lw;
        a1 += att_dst[h * HIDDEN + c] * lw;
        a2 += fc_w[h * HIDDEN + c] * lw;
    }
    w_all[(0 + h) * F_IN + f] = a0;
    w_all[(4 + h) * F_IN + f] = a1;
    w_all[(8 + h) * F_IN + f] = a2;
    if (h == 0) {
        red[f] = bias[f] * fc_w[f];
        __syncthreads();
        for (int s = 128; s; s >>= 1) {
            if (f < s) red[f] += red[f + s];
            __syncthreads();
        }
        if (f == 0) c0[0] = red[0] + fc_b[0];
    }
}

// ---- K1: per-node 256x12 matvec; w_all staged in LDS (12 KB/block) ----
// 1 node per 16-lane group (keeps VGPR ~64); w redundancy served by LDS
// broadcast instead of L1 (the R6 register-blocking blew VGPR to 192 ->
// 9.7% occupancy; this keeps the R5 register shape).
__global__ __launch_bounds__(256) void node_kernel(
        const float* __restrict__ x, const float* __restrict__ w_all,
        float* __restrict__ srcfeat, float* __restrict__ dstfeat) {
    __shared__ float4 lw[768];  // 12 rows x 64 float4 = 12 KB
    int t = threadIdx.x;
    {
        const float4* wr = (const float4*)w_all;
        lw[t] = wr[t];
        lw[t + 256] = wr[t + 256];
        lw[t + 512] = wr[t + 512];
    }
    __syncthreads();
    int tid  = blockIdx.x * 256 + t;
    int wave = tid >> 6;
    int lane = t & 63;
    int sub  = lane >> 4;
    int l16  = lane & 15;
    int n = wave * 4 + sub;
    if (n >= N_NODES) return;
    const float4* xr = (const float4*)x + (size_t)n * 64;
    float p[12];
#pragma unroll
    for (int r = 0; r < 12; ++r) p[r] = 0.f;
#pragma unroll
    for (int k = 0; k < 4; ++k) {
        float4 xv = xr[l16 + 16 * k];
#pragma unroll
        for (int r = 0; r < 12; ++r) {
            float4 wv = lw[r * 64 + l16 + 16 * k];
            p[r] += xv.x * wv.x + xv.y * wv.y + xv.z * wv.z + xv.w * wv.w;
        }
    }
#pragma unroll
    for (int r = 0; r < 12; ++r) {
        float v = p[r];
        v += __shfl_xor(v, 1);
        v += __shfl_xor(v, 2);
        v += __shfl_xor(v, 4);
        v += __shfl_xor(v, 8);
        p[r] = v;
    }
    if (l16 == 0) {
        float4* sf = (float4*)(srcfeat + (size_t)n * 8);
        sf[0] = make_float4(p[0], p[1], p[2], p[3]);
        sf[1] = make_float4(p[8], p[9], p[10], p[11]);
        *(float4*)(dstfeat + (size_t)n * 4) = make_float4(p[4], p[5], p[6], p[7]);
    }
}

// =================== LDS-privatized counting sort (bucket = 128 nodes) ===================

__global__ __launch_bounds__(256) void hist2_kernel(
        const int* __restrict__ ei, int* __restrict__ hist) {
    __shared__ int lcnt[W_BUCKETS];
    int t = threadIdx.x, b = blockIdx.x;
    for (int i = t; i < W_BUCKETS; i += 256) lcnt[i] = 0;
    __syncthreads();
    int base = b * CHUNK;
    int end = base + CHUNK; if (end > N_EDGES) end = N_EDGES;
    for (int e = base + t; e < end; e += 256)
        atomicAdd(&lcnt[ei[N_EDGES + e] >> BSHIFT], 1);
    __syncthreads();
    for (int i = t; i < W_BUCKETS; i += 256) hist[i * B_SC + b] = lcnt[i];
}

__global__ __launch_bounds__(256) void scan1_kernel(
        const int* __restrict__ hist, int* __restrict__ bsum) {
    __shared__ int red[256];
    int t = threadIdx.x, b = blockIdx.x;
    int i = b * 256 + t;
    red[t] = (i < M_OFF) ? hist[i] : 0;
    __syncthreads();
    for (int s = 128; s; s >>= 1) {
        if (t < s) red[t] += red[t + s];
        __syncthreads();
    }
    if (t == 0) bsum[b] = red[0];
}

// exclusive scan of NB1 block sums; 1024 threads x 2 serial
__global__ __launch_bounds__(1024) void scan2_kernel(int* __restrict__ bsum) {
    __shared__ int sc[1024];
    int t = threadIdx.x;
    int i0 = t * 2, i1 = t * 2 + 1;
    int v0 = (i0 < NB1) ? bsum[i0] : 0;
    int v1 = (i1 < NB1) ? bsum[i1] : 0;
    int s = v0 + v1;
    sc[t] = s;
    __syncthreads();
    for (int off = 1; off < 1024; off <<= 1) {
        int tmp = (t >= off) ? sc[t - off] : 0;
        __syncthreads();
        sc[t] += tmp;
        __syncthreads();
    }
    int base = sc[t] - s;  // exclusive
    if (i0 < NB1) bsum[i0] = base;
    if (i1 < NB1) bsum[i1] = base + v0;
}

__global__ __launch_bounds__(256) void scan3_kernel(
        int* __restrict__ hist, const int* __restrict__ bsum) {
    __shared__ int sc[256];
    int t = threadIdx.x, b = blockIdx.x;
    int i = b * 256 + t;
    int v = (i < M_OFF) ? hist[i] : 0;
    sc[t] = v;
    __syncthreads();
    for (int off = 1; off < 256; off <<= 1) {
        int tmp = (t >= off) ? sc[t - off] : 0;
        __syncthreads();
        sc[t] += tmp;
        __syncthreads();
    }
    if (i < M_OFF) hist[i] = bsum[b] + sc[t] - v;
}

// place edges: sorted[pos] = src | (dst&127)<<17
__global__ __launch_bounds__(256) void scatter2_kernel(
        const int* __restrict__ ei, const int* __restrict__ goff,
        int* __restrict__ sorted) {
    __shared__ int lbase[W_BUCKETS];
    int t = threadIdx.x, b = blockIdx.x;
    for (int i = t; i < W_BUCKETS; i += 256) lbase[i] = goff[i * B_SC + b];
    __syncthreads();
    int base = b * CHUNK;
    int end = base + CHUNK; if (end > N_EDGES) end = N_EDGES;
    for (int e = base + t; e < end; e += 256) {
        int s = ei[e];
        int d = ei[N_EDGES + e];
        int pos = atomicAdd(&lbase[d >> BSHIFT], 1);
        sorted[pos] = s | ((d & BMASK) << 17);
    }
}

// ---- agg4: per-bucket in-LDS fine sort + atomic-free per-node aggregation ----
__global__ __launch_bounds__(256) void agg4_kernel(
        const int* __restrict__ sorted, const int* __restrict__ goff,
        const float* __restrict__ srcfeat, const float* __restrict__ dstfeat,
        const float* __restrict__ c0, float* __restrict__ out) {
    __shared__ int eds[CAP];
    __shared__ int srt[CAP];
    __shared__ int cnt[128];   // hist, then cursor
    __shared__ int bnd[129];   // exclusive bounds
    int t = threadIdx.x, k = blockIdx.x;
    int begin = goff[k * B_SC];
    int end = (k == W_BUCKETS - 1) ? N_EDGES : goff[(k + 1) * B_SC];
    int len = end - begin;
    int lcap = len < CAP ? len : CAP;
    if (t < 128) cnt[t] = 0;
    __syncthreads();
    for (int i = t; i < lcap; i += 256) {
        int p = sorted[begin + i];
        eds[i] = p;
        atomicAdd(&cnt[p >> 17], 1);
    }
    __syncthreads();
    if (t < 128) bnd[t + 1] = cnt[t];
    __syncthreads();
    for (int off = 1; off < 128; off <<= 1) {
        int v = 0;
        if (t < 128 && t >= off) v = bnd[t + 1 - off];
        __syncthreads();
        if (t < 128) bnd[t + 1] += v;
        __syncthreads();
    }
    if (t == 0) bnd[0] = 0;
    if (t < 128) cnt[t] = (t == 0) ? 0 : bnd[t];
    __syncthreads();
    for (int i = t; i < lcap; i += 256) {
        int p = eds[i];
        int pos = atomicAdd(&cnt[p >> 17], 1);
        srt[pos] = p & 0x1FFFF;
    }
    __syncthreads();
    if (t < 128) {
        int n0 = k * 128 + t;
        if (n0 < N_NODES) {
            float4 ad = *(const float4*)(dstfeat + (size_t)n0 * 4);
            float de0 = 0.f, de1 = 0.f, de2 = 0.f, de3 = 0.f;
            float nu0 = 0.f, nu1 = 0.f, nu2 = 0.f, nu3 = 0.f;
            int b0 = bnd[t], e0 = bnd[t + 1];
            for (int i = b0; i < e0; ++i) {
                int s = srt[i];
                const float4* sp = (const float4*)(srcfeat + (size_t)s * 8);
                float4 as = sp[0];
                float4 g  = sp[1];
                float s0 = as.x + ad.x, s1 = as.y + ad.y;
                float s2 = as.z + ad.z, s3 = as.w + ad.w;
                float x0 = __expf(s0 > 0.f ? s0 : NEG_SLOPE * s0);
                float x1 = __expf(s1 > 0.f ? s1 : NEG_SLOPE * s1);
                float x2 = __expf(s2 > 0.f ? s2 : NEG_SLOPE * s2);
                float x3 = __expf(s3 > 0.f ? s3 : NEG_SLOPE * s3);
                de0 += x0; de1 += x1; de2 += x2; de3 += x3;
                nu0 += x0 * g.x; nu1 += x1 * g.y; nu2 += x2 * g.z; nu3 += x3 * g.w;
            }
            for (int i = CAP; i < len; ++i) {
                int p = sorted[begin + i];
                if ((p >> 17) == t) {
                    int s = p & 0x1FFFF;
                    const float4* sp = (const float4*)(srcfeat + (size_t)s * 8);
                    float4 as = sp[0];
                    float4 g  = sp[1];
                    float s0 = as.x + ad.x, s1 = as.y + ad.y;
                    float s2 = as.z + ad.z, s3 = as.w + ad.w;
                    float x0 = __expf(s0 > 0.f ? s0 : NEG_SLOPE * s0);
                    float x1 = __expf(s1 > 0.f ? s1 : NEG_SLOPE * s1);
                    float x2 = __expf(s2 > 0.f ? s2 : NEG_SLOPE * s2);
                    float x3 = __expf(s3 > 0.f ? s3 : NEG_SLOPE * s3);
                    de0 += x0; de1 += x1; de2 += x2; de3 += x3;
                    nu0 += x0 * g.x; nu1 += x1 * g.y; nu2 += x2 * g.z; nu3 += x3 * g.w;
                }
            }
            float y = c0[0]
                    + nu0 / (de0 + 1e-16f)
                    + nu1 / (de1 + 1e-16f)
                    + nu2 / (de2 + 1e-16f)
                    + nu3 / (de3 + 1e-16f);
            out[n0] = y;
        }
    }
}

// =================== fallback atomic path (tiny ws) ===================

__global__ __launch_bounds__(256) void init_nd_kernel(
        float* __restrict__ num, float* __restrict__ den) {
    int i = blockIdx.x * 256 + threadIdx.x;
    if (i < N_NODES * 4) { num[i] = 0.f; den[i] = 0.f; }
}

__global__ __launch_bounds__(256) void edge_acc2_kernel(
        const int* __restrict__ ei, const float* __restrict__ srcfeat,
        const float* __restrict__ dstfeat, float* __restrict__ num,
        float* __restrict__ den) {
    int e = blockIdx.x * 256 + threadIdx.x;
    if (e >= N_EDGES) return;
    int s = ei[e];
    int d = ei[N_EDGES + e];
    const float4* sp = (const float4*)(srcfeat + (size_t)s * 8);
    float4 as = sp[0];
    float4 g  = sp[1];
    float4 ad = *(const float4*)(dstfeat + (size_t)d * 4);
    float sc[4] = {as.x + ad.x, as.y + ad.y, as.z + ad.z, as.w + ad.w};
    float gg[4] = {g.x, g.y, g.z, g.w};
    float* np = num + (size_t)d * 4;
    float* dp = den + (size_t)d * 4;
#pragma unroll
    for (int h = 0; h < 4; ++h) {
        float v = sc[h] > 0.f ? sc[h] : NEG_SLOPE * sc[h];
        float ex = __expf(v);
        atomicAdd(dp + h, ex);
        atomicAdd(np + h, ex * gg[h]);
    }
}

__global__ __launch_bounds__(256) void finalize_kernel(
        const float* __restrict__ num, const float* __restrict__ den,
        const float* __restrict__ c0, float* __restrict__ out) {
    int n = blockIdx.x * 256 + threadIdx.x;
    if (n >= N_NODES) return;
    float4 nu = *(const float4*)(num + (size_t)n * 4);
    float4 de = *(const float4*)(den + (size_t)n * 4);
    out[n] = c0[0]
           + nu.x / (de.x + 1e-16f)
           + nu.y / (de.y + 1e-16f)
           + nu.z / (de.z + 1e-16f)
           + nu.w / (de.w + 1e-16f);
}

extern "C" void kernel_launch(void* const* d_in, const int* in_sizes, int n_in,
                              void* d_out, int out_size, void* d_ws, size_t ws_size,
                              hipStream_t stream) {
    const float* x       = (const float*)d_in[0];
    const int*   ei      = (const int*)d_in[1];
    const float* lin_w   = (const float*)d_in[2];
    const float* att_src = (const float*)d_in[3];
    const float* att_dst = (const float*)d_in[4];
    const float* bias    = (const float*)d_in[5];
    const float* fc_w    = (const float*)d_in[6];
    const float* fc_b    = (const float*)d_in[7];
    float* out = (float*)d_out;

    float* ws = (float*)d_ws;
    float* w_all   = ws;            // 3072 (+pad to 4096)
    float* c0      = ws + 3072;
    float* srcfeat = ws + 4096;     // 800000
    float* dstfeat = ws + 804096;   // 400000

    prep_kernel<<<4, 256, 0, stream>>>(lin_w, att_src, att_dst, fc_w, bias, fc_b, w_all, c0);
    // 4 nodes per wave, 16 nodes per block
    node_kernel<<<(N_NODES + 15) / 16, 256, 0, stream>>>(x, w_all, srcfeat, dstfeat);

    // layout: hist @1204096 (400384) | bsum @1604480 (1564, pad) | sorted @1606144 (1600000)
    const size_t need_words = 3206144;
    if (ws_size >= need_words * 4) {
        int* hist   = (int*)(ws + 1204096);
        int* bsum   = (int*)(ws + 1604480);
        int* sorted = (int*)(ws + 1606144);

        hist2_kernel<<<B_SC, 256, 0, stream>>>(ei, hist);
        scan1_kernel<<<NB1, 256, 0, stream>>>(hist, bsum);
        scan2_kernel<<<1, 1024, 0, stream>>>(bsum);
        scan3_kernel<<<NB1, 256, 0, stream>>>(hist, bsum);
        scatter2_kernel<<<B_SC, 256, 0, stream>>>(ei, hist, sorted);
        agg4_kernel<<<W_BUCKETS, 256, 0, stream>>>(sorted, hist, srcfeat, dstfeat, c0, out);
    } else {
        float* num = ws + 1204096;
        float* den = ws + 1604096;
        init_nd_kernel<<<(N_NODES * 4 + 255) / 256, 256, 0, stream>>>(num, den);
        edge_acc2_kernel<<<N_EDGES / 256, 256, 0, stream>>>(ei, srcfeat, dstfeat, num, den);
        finalize_kernel<<<(N_NODES + 255) / 256, 256, 0, stream>>>(num, den, c0, out);
    }
}

// Round 8
// 241.384 us; speedup vs baseline: 1.3024x; 1.0087x over previous
//
#include <hip/hip_runtime.h>
#include <math.h>

#define N_NODES 100000
#define N_EDGES 1600000
#define F_IN 256
#define HIDDEN 64
#define NEG_SLOPE 0.2f

#define BSHIFT 7               // bucket = dst>>7 (128 nodes/bucket)
#define BMASK 127
#define W_BUCKETS 782          // ceil(100000/128)
#define B_SC 512               // hist/scatter blocks (must be 64*8 for scanb)
#define CHUNK 3125             // 512*3125 = 1600000 exactly
#define M_OFF (W_BUCKETS * B_SC)  // 400384
#define CAP 2560               // fixed slots per bucket (mean 2045, +11 sigma)

// ---- K0: fold att_src/att_dst/fc_w through lin_w ----
__global__ __launch_bounds__(256) void prep_kernel(
        const float* __restrict__ lin_w, const float* __restrict__ att_src,
        const float* __restrict__ att_dst, const float* __restrict__ fc_w,
        const float* __restrict__ bias, const float* __restrict__ fc_b,
        float* __restrict__ w_all, float* __restrict__ c0) {
    __shared__ float red[256];
    int h = blockIdx.x;   // 0..3
    int f = threadIdx.x;  // 0..255
    float a0 = 0.f, a1 = 0.f, a2 = 0.f;
    for (int c = 0; c < HIDDEN; ++c) {
        float lw = lin_w[(size_t)(h * HIDDEN + c) * F_IN + f];
        a0 += att_src[h * HIDDEN + c] * lw;
        a1 += att_dst[h * HIDDEN + c] * lw;
        a2 += fc_w[h * HIDDEN + c] * lw;
    }
    w_all[(0 + h) * F_IN + f] = a0;
    w_all[(4 + h) * F_IN + f] = a1;
    w_all[(8 + h) * F_IN + f] = a2;
    if (h == 0) {
        red[f] = bias[f] * fc_w[f];
        __syncthreads();
        for (int s = 128; s; s >>= 1) {
            if (f < s) red[f] += red[f + s];
            __syncthreads();
        }
        if (f == 0) c0[0] = red[0] + fc_b[0];
    }
}

// ---- K1: per-node 256x12 matvec; w_all staged in LDS (12 KB/block) ----
__global__ __launch_bounds__(256) void node_kernel(
        const float* __restrict__ x, const float* __restrict__ w_all,
        float* __restrict__ srcfeat, float* __restrict__ dstfeat) {
    __shared__ float4 lw[768];  // 12 rows x 64 float4 = 12 KB
    int t = threadIdx.x;
    {
        const float4* wr = (const float4*)w_all;
        lw[t] = wr[t];
        lw[t + 256] = wr[t + 256];
        lw[t + 512] = wr[t + 512];
    }
    __syncthreads();
    int tid  = blockIdx.x * 256 + t;
    int wave = tid >> 6;
    int lane = t & 63;
    int sub  = lane >> 4;
    int l16  = lane & 15;
    int n = wave * 4 + sub;
    if (n >= N_NODES) return;
    const float4* xr = (const float4*)x + (size_t)n * 64;
    float p[12];
#pragma unroll
    for (int r = 0; r < 12; ++r) p[r] = 0.f;
#pragma unroll
    for (int k = 0; k < 4; ++k) {
        float4 xv = xr[l16 + 16 * k];
#pragma unroll
        for (int r = 0; r < 12; ++r) {
            float4 wv = lw[r * 64 + l16 + 16 * k];
            p[r] += xv.x * wv.x + xv.y * wv.y + xv.z * wv.z + xv.w * wv.w;
        }
    }
#pragma unroll
    for (int r = 0; r < 12; ++r) {
        float v = p[r];
        v += __shfl_xor(v, 1);
        v += __shfl_xor(v, 2);
        v += __shfl_xor(v, 4);
        v += __shfl_xor(v, 8);
        p[r] = v;
    }
    if (l16 == 0) {
        float4* sf = (float4*)(srcfeat + (size_t)n * 8);
        sf[0] = make_float4(p[0], p[1], p[2], p[3]);
        sf[1] = make_float4(p[8], p[9], p[10], p[11]);
        *(float4*)(dstfeat + (size_t)n * 4) = make_float4(p[4], p[5], p[6], p[7]);
    }
}

// =================== counting sort, static bucket regions ===================
// hist layout (TRANSPOSED vs earlier rounds): hist[b * W_BUCKETS + k]
//  -> hist2 stores and scatter2 loads are contiguous per block.

__global__ __launch_bounds__(256) void hist2_kernel(
        const int* __restrict__ ei, int* __restrict__ hist) {
    __shared__ int lcnt[W_BUCKETS];
    int t = threadIdx.x, b = blockIdx.x;
    for (int i = t; i < W_BUCKETS; i += 256) lcnt[i] = 0;
    __syncthreads();
    int base = b * CHUNK;
    int end = base + CHUNK; if (end > N_EDGES) end = N_EDGES;
    for (int e = base + t; e < end; e += 256)
        atomicAdd(&lcnt[ei[N_EDGES + e] >> BSHIFT], 1);
    __syncthreads();
    int* hb = hist + (size_t)b * W_BUCKETS;
    for (int i = t; i < W_BUCKETS; i += 256) hb[i] = lcnt[i];
}

// One wave per bucket: exclusive scan of the 512 per-block counts (8/lane),
// rebased to the bucket's static region k*CAP. Writes bucket total to bcnt.
// Also zeroes the overflow counter (runs before scatter2 in stream order).
__global__ __launch_bounds__(256) void scanb_kernel(
        int* __restrict__ hist, int* __restrict__ bcnt, int* __restrict__ ocnt) {
    if (blockIdx.x == 0 && threadIdx.x == 0) *ocnt = 0;
    int wv = (blockIdx.x * 256 + threadIdx.x) >> 6;  // bucket id
    int lane = threadIdx.x & 63;
    if (wv >= W_BUCKETS) return;
    int base = lane * 8;   // first block index this lane handles
    int v[8];
#pragma unroll
    for (int j = 0; j < 8; ++j)
        v[j] = hist[(size_t)(base + j) * W_BUCKETS + wv];
    int s[8];
    s[0] = v[0];
#pragma unroll
    for (int j = 1; j < 8; ++j) s[j] = s[j - 1] + v[j];
    int tot = s[7];
    int incl = tot;
#pragma unroll
    for (int off = 1; off < 64; off <<= 1) {
        int tmp = __shfl_up(incl, off);
        if (lane >= off) incl += tmp;
    }
    int excl = incl - tot;
    int b0 = wv * CAP;
#pragma unroll
    for (int j = 0; j < 8; ++j) {
        int pref = (j == 0) ? 0 : s[j - 1];
        hist[(size_t)(base + j) * W_BUCKETS + wv] = b0 + excl + pref;
    }
    if (lane == 63) bcnt[wv] = incl;  // inclusive over all lanes = bucket total
}

// place edges into static bucket regions: sorted[pos] = src | (dst&127)<<17
__global__ __launch_bounds__(256) void scatter2_kernel(
        const int* __restrict__ ei, const int* __restrict__ goff,
        int* __restrict__ sorted, int* __restrict__ ocnt,
        int2* __restrict__ obuf) {
    __shared__ int lbase[W_BUCKETS];
    int t = threadIdx.x, b = blockIdx.x;
    const int* gb = goff + (size_t)b * W_BUCKETS;
    for (int i = t; i < W_BUCKETS; i += 256) lbase[i] = gb[i];
    __syncthreads();
    int base = b * CHUNK;
    int end = base + CHUNK; if (end > N_EDGES) end = N_EDGES;
    for (int e = base + t; e < end; e += 256) {
        int s = ei[e];
        int d = ei[N_EDGES + e];
        int k = d >> BSHIFT;
        int pos = atomicAdd(&lbase[k], 1);
        if (pos < (k + 1) * CAP) {
            sorted[pos] = s | ((d & BMASK) << 17);
        } else {                       // bucket overflow (never for this input)
            int oi = atomicAdd(ocnt, 1);
            obuf[oi] = make_int2(s, d);
        }
    }
}

// ---- agg4: per-bucket in-LDS fine sort + atomic-free per-node aggregation ----
__global__ __launch_bounds__(256) void agg4_kernel(
        const int* __restrict__ sorted, const int* __restrict__ bcnt,
        const float* __restrict__ srcfeat, const float* __restrict__ dstfeat,
        const float* __restrict__ c0, float* __restrict__ out,
        const int* __restrict__ ocnt, const int2* __restrict__ obuf) {
    __shared__ int eds[CAP];
    __shared__ int srt[CAP];
    __shared__ int cnt[128];   // hist, then cursor
    __shared__ int bnd[129];   // exclusive bounds
    __shared__ int s_oc;
    int t = threadIdx.x, k = blockIdx.x;
    if (t == 0) s_oc = *ocnt;
    int begin = k * CAP;
    int len = bcnt[k];
    int lcap = len < CAP ? len : CAP;
    if (t < 128) cnt[t] = 0;
    __syncthreads();
    for (int i = t; i < lcap; i += 256) {
        int p = sorted[begin + i];
        eds[i] = p;
        atomicAdd(&cnt[p >> 17], 1);
    }
    __syncthreads();
    if (t < 128) bnd[t + 1] = cnt[t];
    __syncthreads();
    for (int off = 1; off < 128; off <<= 1) {
        int v = 0;
        if (t < 128 && t >= off) v = bnd[t + 1 - off];
        __syncthreads();
        if (t < 128) bnd[t + 1] += v;
        __syncthreads();
    }
    if (t == 0) bnd[0] = 0;
    if (t < 128) cnt[t] = (t == 0) ? 0 : bnd[t];
    __syncthreads();
    for (int i = t; i < lcap; i += 256) {
        int p = eds[i];
        int pos = atomicAdd(&cnt[p >> 17], 1);
        srt[pos] = p & 0x1FFFF;
    }
    __syncthreads();
    if (t < 128) {
        int n0 = k * 128 + t;
        if (n0 < N_NODES) {
            float4 ad = *(const float4*)(dstfeat + (size_t)n0 * 4);
            float de0 = 0.f, de1 = 0.f, de2 = 0.f, de3 = 0.f;
            float nu0 = 0.f, nu1 = 0.f, nu2 = 0.f, nu3 = 0.f;
            int b0 = bnd[t], e0 = bnd[t + 1];
            for (int i = b0; i < e0; ++i) {
                int s = srt[i];
                const float4* sp = (const float4*)(srcfeat + (size_t)s * 8);
                float4 as = sp[0];
                float4 g  = sp[1];
                float s0 = as.x + ad.x, s1 = as.y + ad.y;
                float s2 = as.z + ad.z, s3 = as.w + ad.w;
                float x0 = __expf(s0 > 0.f ? s0 : NEG_SLOPE * s0);
                float x1 = __expf(s1 > 0.f ? s1 : NEG_SLOPE * s1);
                float x2 = __expf(s2 > 0.f ? s2 : NEG_SLOPE * s2);
                float x3 = __expf(s3 > 0.f ? s3 : NEG_SLOPE * s3);
                de0 += x0; de1 += x1; de2 += x2; de3 += x3;
                nu0 += x0 * g.x; nu1 += x1 * g.y; nu2 += x2 * g.z; nu3 += x3 * g.w;
            }
            // overflow edges (empty in practice)
            for (int i = 0; i < s_oc; ++i) {
                int2 e = obuf[i];
                if ((e.y >> BSHIFT) == k && (e.y & BMASK) == t) {
                    const float4* sp = (const float4*)(srcfeat + (size_t)e.x * 8);
                    float4 as = sp[0];
                    float4 g  = sp[1];
                    float s0 = as.x + ad.x, s1 = as.y + ad.y;
                    float s2 = as.z + ad.z, s3 = as.w + ad.w;
                    float x0 = __expf(s0 > 0.f ? s0 : NEG_SLOPE * s0);
                    float x1 = __expf(s1 > 0.f ? s1 : NEG_SLOPE * s1);
                    float x2 = __expf(s2 > 0.f ? s2 : NEG_SLOPE * s2);
                    float x3 = __expf(s3 > 0.f ? s3 : NEG_SLOPE * s3);
                    de0 += x0; de1 += x1; de2 += x2; de3 += x3;
                    nu0 += x0 * g.x; nu1 += x1 * g.y; nu2 += x2 * g.z; nu3 += x3 * g.w;
                }
            }
            float y = c0[0]
                    + nu0 / (de0 + 1e-16f)
                    + nu1 / (de1 + 1e-16f)
                    + nu2 / (de2 + 1e-16f)
                    + nu3 / (de3 + 1e-16f);
            out[n0] = y;
        }
    }
}

// =================== fallback atomic path (tiny ws) ===================

__global__ __launch_bounds__(256) void init_nd_kernel(
        float* __restrict__ num, float* __restrict__ den) {
    int i = blockIdx.x * 256 + threadIdx.x;
    if (i < N_NODES * 4) { num[i] = 0.f; den[i] = 0.f; }
}

__global__ __launch_bounds__(256) void edge_acc2_kernel(
        const int* __restrict__ ei, const float* __restrict__ srcfeat,
        const float* __restrict__ dstfeat, float* __restrict__ num,
        float* __restrict__ den) {
    int e = blockIdx.x * 256 + threadIdx.x;
    if (e >= N_EDGES) return;
    int s = ei[e];
    int d = ei[N_EDGES + e];
    const float4* sp = (const float4*)(srcfeat + (size_t)s * 8);
    float4 as = sp[0];
    float4 g  = sp[1];
    float4 ad = *(const float4*)(dstfeat + (size_t)d * 4);
    float sc[4] = {as.x + ad.x, as.y + ad.y, as.z + ad.z, as.w + ad.w};
    float gg[4] = {g.x, g.y, g.z, g.w};
    float* np = num + (size_t)d * 4;
    float* dp = den + (size_t)d * 4;
#pragma unroll
    for (int h = 0; h < 4; ++h) {
        float v = sc[h] > 0.f ? sc[h] : NEG_SLOPE * sc[h];
        float ex = __expf(v);
        atomicAdd(dp + h, ex);
        atomicAdd(np + h, ex * gg[h]);
    }
}

__global__ __launch_bounds__(256) void finalize_kernel(
        const float* __restrict__ num, const float* __restrict__ den,
        const float* __restrict__ c0, float* __restrict__ out) {
    int n = blockIdx.x * 256 + threadIdx.x;
    if (n >= N_NODES) return;
    float4 nu = *(const float4*)(num + (size_t)n * 4);
    float4 de = *(const float4*)(den + (size_t)n * 4);
    out[n] = c0[0]
           + nu.x / (de.x + 1e-16f)
           + nu.y / (de.y + 1e-16f)
           + nu.z / (de.z + 1e-16f)
           + nu.w / (de.w + 1e-16f);
}

extern "C" void kernel_launch(void* const* d_in, const int* in_sizes, int n_in,
                              void* d_out, int out_size, void* d_ws, size_t ws_size,
                              hipStream_t stream) {
    const float* x       = (const float*)d_in[0];
    const int*   ei      = (const int*)d_in[1];
    const float* lin_w   = (const float*)d_in[2];
    const float* att_src = (const float*)d_in[3];
    const float* att_dst = (const float*)d_in[4];
    const float* bias    = (const float*)d_in[5];
    const float* fc_w    = (const float*)d_in[6];
    const float* fc_b    = (const float*)d_in[7];
    float* out = (float*)d_out;

    float* ws = (float*)d_ws;
    float* w_all   = ws;            // 3072 (+pad to 4096)
    float* c0      = ws + 3072;
    float* srcfeat = ws + 4096;     // 800000
    float* dstfeat = ws + 804096;   // 400000

    prep_kernel<<<4, 256, 0, stream>>>(lin_w, att_src, att_dst, fc_w, bias, fc_b, w_all, c0);
    node_kernel<<<(N_NODES + 15) / 16, 256, 0, stream>>>(x, w_all, srcfeat, dstfeat);

    // layout (words from ws base):
    // hist   @1204096  (400384)   -> 1604480
    // bcnt   @1604480  (1024 pad) -> 1605504
    // ocnt   @1605504  (64 pad)   -> 1605568
    // obuf   @1605568  (3200000)  -> 4805568   (int2 x N_EDGES, 8B-aligned)
    // sorted @4805568  (2001920)  -> 6807488   (~27.2 MB total)
    const size_t need_words = 6807488;
    if (ws_size >= need_words * 4) {
        int*  hist   = (int*)(ws + 1204096);
        int*  bcnt   = (int*)(ws + 1604480);
        int*  ocnt   = (int*)(ws + 1605504);
        int2* obuf   = (int2*)(ws + 1605568);
        int*  sorted = (int*)(ws + 4805568);

        hist2_kernel<<<B_SC, 256, 0, stream>>>(ei, hist);
        scanb_kernel<<<(W_BUCKETS + 3) / 4, 256, 0, stream>>>(hist, bcnt, ocnt);
        scatter2_kernel<<<B_SC, 256, 0, stream>>>(ei, hist, sorted, ocnt, obuf);
        agg4_kernel<<<W_BUCKETS, 256, 0, stream>>>(
            sorted, bcnt, srcfeat, dstfeat, c0, out, ocnt, obuf);
    } else {
        float* num = ws + 1204096;
        float* den = ws + 1604096;
        init_nd_kernel<<<(N_NODES * 4 + 255) / 256, 256, 0, stream>>>(num, den);
        edge_acc2_kernel<<<N_EDGES / 256, 256, 0, stream>>>(ei, srcfeat, dstfeat, num, den);
        finalize_kernel<<<(N_NODES + 255) / 256, 256, 0, stream>>>(num, den, c0, out);
    }
}